// Round 16
// baseline (118.981 us; speedup 1.0000x reference)
//
#include <hip/hip_runtime.h>

#define NNODES 2048
#define NHEAD 8
#define DKDIM 64

typedef unsigned int uint;
typedef unsigned short ushort;
typedef unsigned char uchar;
typedef __fp16 h2 __attribute__((ext_vector_type(2)));
typedef __fp16 h8 __attribute__((ext_vector_type(8)));
typedef float f16v __attribute__((ext_vector_type(16)));

#define KSCALE 0.18033688011112042f   // 0.125 * log2(e)
#define CLAMP2 14.426950408889634f    // 10 * log2(e)

__device__ __forceinline__ uint pk2(float a, float b) {
    union { h2 h; uint u; } x; x.h = __builtin_amdgcn_cvt_pkrtz(a, b); return x.u;
}

// ---- prep1: k -> fp16 [head][node][dim] (pre-scaled) + zero A (2MB) ----
__global__ void prep1(const float* __restrict__ k, uint4* __restrict__ kc,
                      uint4* __restrict__ A4) {
    int i = blockIdx.x * 256 + threadIdx.x;      // 0..131071
    int dim8 = i & 7, node = (i >> 3) & 2047, h = i >> 14;
    const float* src = k + (size_t)node * 512 + h * 64 + dim8 * 8;
    float4 f0 = *(const float4*)src;
    float4 f1 = *(const float4*)(src + 4);
    uint4 o;
    o.x = pk2(f0.x * KSCALE, f0.y * KSCALE);
    o.y = pk2(f0.z * KSCALE, f0.w * KSCALE);
    o.z = pk2(f1.x * KSCALE, f1.y * KSCALE);
    o.w = pk2(f1.z * KSCALE, f1.w * KSCALE);
    kc[(h * 2048 + node) * 8 + dim8] = o;
    uint4 zz = {0u, 0u, 0u, 0u};
    A4[i] = zz;                                   // 131072 * 16B = 2MB
}

// ---- prep2: blocks 0..255 = v -> fp16 transposed [head][dim][node];
//             blocks 256..2303 = histA into A[dst][src] 4-bit nibbles ----
__global__ void prep2(const float* __restrict__ v, ushort* __restrict__ vt,
                      const int* __restrict__ es, const int* __restrict__ ed,
                      uint* __restrict__ A32, int E) {
    __shared__ float tile[64][65];
    int b = blockIdx.x;
    int t = threadIdx.x;
    if (b < 256) {
        int h = b & 7, tn = b >> 3;
        int nl = t >> 2, dq = (t & 3) * 16;
        const float* src = v + ((size_t)(tn * 64 + nl)) * 512 + h * 64 + dq;
#pragma unroll
        for (int i = 0; i < 4; ++i) {
            float4 f = *(const float4*)(src + i * 4);
            tile[nl][dq + i * 4 + 0] = f.x;
            tile[nl][dq + i * 4 + 1] = f.y;
            tile[nl][dq + i * 4 + 2] = f.z;
            tile[nl][dq + i * 4 + 3] = f.w;
        }
        __syncthreads();
        int dim = t >> 2, nq = (t & 3) * 16;
        uint wv[8];
#pragma unroll
        for (int i = 0; i < 8; ++i)
            wv[i] = pk2(tile[nq + 2 * i][dim], tile[nq + 2 * i + 1][dim]);
        char* base = (char*)vt + ((size_t)(b & 7) * 64 + dim) * 4096 + (b >> 3) * 128;
        int nb0 = (t & 3) * 2;
        uint4 lo = { wv[0], wv[1], wv[2], wv[3] };
        uint4 hi = { wv[4], wv[5], wv[6], wv[7] };
        *(uint4*)(base + nb0 * 16) = lo;
        *(uint4*)(base + nb0 * 16 + 16) = hi;
    } else {
        int i = (b - 256) * 256 + t;
        if (i < E) {
            uint idx = (uint)ed[i] * 2048u + (uint)es[i];   // nibble index [dst][src]
            atomicAdd(&A32[idx >> 3], 1u << ((idx & 7) * 4));
        }
    }
}

// ---- dense masked attention, 32x32x16 MFMA, reg-resident 4-bit mask ----
// (identical to R15; launched 3x this round PURELY to measure its duration
//  by dur_us differencing: A = (dur - 63.6)/2)
__global__ void __launch_bounds__(512, 4) attn_kernel(
    const float* __restrict__ q, const ushort* __restrict__ kc, const ushort* __restrict__ vt,
    const uchar* __restrict__ A8, float* __restrict__ out) {
    __shared__ __align__(16) char LK[2][2][8192];   // [half][buf][64 src x 128B] swz
    __shared__ __align__(16) char LV[2][2][8192];   // [half][buf][64 dim x 128B] swz

    int b = blockIdx.x;
    int j = b & 7, idx = b >> 3;
    int dt = (j & 3) * 8 + (idx >> 2);
    int h = (j >> 2) * 4 + (idx & 3);
    int dst0 = dt * 64;
    int t = threadIdx.x;
    int w = t >> 6, half = w >> 2;
    int u = w & 3, sr = u >> 1, dc = u & 1;
    int l = t & 63, lm = l & 31, hi = l >> 5;
    int ht = t & 255;

    const char* kH = (const char*)kc + (size_t)h * 262144;
    const char* vH = (const char*)vt + (size_t)h * 262144;
    const char* aRow = (const char*)A8 + (size_t)(dst0 + dc * 32 + lm) * 1024 + sr * 16;

    // Q frags: qf[jq] = Q[dst0+dc*32+lm][dim jq*16 + hi*8 .. +7]
    h8 qf[4];
    {
        const float* qp = q + (size_t)(dst0 + dc * 32 + lm) * 512 + h * 64 + hi * 8;
#pragma unroll
        for (int jq = 0; jq < 4; ++jq) {
            float4 f0 = *(const float4*)(qp + jq * 16);
            float4 f1 = *(const float4*)(qp + jq * 16 + 4);
            union { uint u4[4]; h8 v; } U;
            U.u4[0] = pk2(f0.x, f0.y); U.u4[1] = pk2(f0.z, f0.w);
            U.u4[2] = pk2(f1.x, f1.y); U.u4[3] = pk2(f1.z, f1.w);
            qf[jq] = U.v;
        }
    }

    f16v of[2];
#pragma unroll
    for (int dg = 0; dg < 2; ++dg)
#pragma unroll
        for (int i = 0; i < 16; ++i) of[dg][i] = 0.f;
    float z = 0.f;

    int r0 = ht >> 3, b0 = ht & 7;     // K/V staging: rows r0, r0+32; block b0
    int ts0 = half * 16;
    uint4 kr[2], vr[2];
    uint4 ac, an;

    // prologue: stage tile ts0 into buf 0 (swz: blk ^= row&7); A tile in regs
#pragma unroll
    for (int jj = 0; jj < 2; ++jj) {
        int row = r0 + jj * 32;
        kr[jj] = *(const uint4*)(kH + (size_t)(ts0 * 64 + row) * 128 + b0 * 16);
        vr[jj] = *(const uint4*)(vH + (size_t)row * 4096 + ts0 * 128 + b0 * 16);
        *(uint4*)(LK[half][0] + row * 128 + (b0 ^ (row & 7)) * 16) = kr[jj];
        *(uint4*)(LV[half][0] + row * 128 + (b0 ^ (row & 7)) * 16) = vr[jj];
    }
    ac = *(const uint4*)(aRow + ts0 * 32);
    __syncthreads();

    for (int it = 0; it < 16; ++it) {
        int cur = it & 1;
        int ts = ts0 + it;
        // issue next-tile global loads early
        if (it < 15) {
#pragma unroll
            for (int jj = 0; jj < 2; ++jj) {
                int row = r0 + jj * 32;
                kr[jj] = *(const uint4*)(kH + (size_t)((ts + 1) * 64 + row) * 128 + b0 * 16);
                vr[jj] = *(const uint4*)(vH + (size_t)row * 4096 + (ts + 1) * 128 + b0 * 16);
            }
            an = *(const uint4*)(aRow + (ts + 1) * 32);
        }

        // QK^T: sacc lane (dst=dc*32+lm, hi) reg -> src = sr*32+(reg&3)+8*(reg>>2)+4hi
        f16v sacc;
#pragma unroll
        for (int i = 0; i < 16; ++i) sacc[i] = 0.f;
        __builtin_amdgcn_s_setprio(1);
#pragma unroll
        for (int jq = 0; jq < 4; ++jq) {
            h8 kf = *(const h8*)(LK[half][cur] + (sr * 32 + lm) * 128 +
                                 (((2 * jq + hi) ^ (lm & 7)) * 16));
            sacc = __builtin_amdgcn_mfma_f32_32x32x16_f16(kf, qf[jq], sacc, 0, 0, 0);
        }
        __builtin_amdgcn_s_setprio(0);

        // exp + 4-bit multiplicity mask (from registers) + z; pack W[G][p]
        uint W[4][2];
        {
            const uint* aw4 = (const uint*)&ac;
#pragma unroll
            for (int G = 0; G < 4; ++G) {
                uint aw = aw4[G];
                float ee[4];
#pragma unroll
                for (int j2 = 0; j2 < 4; ++j2) {
                    float sc = fminf(fmaxf(sacc[4 * G + j2], -CLAMP2), CLAMP2);
                    ee[j2] = exp2f(sc) * (float)((aw >> (16 * hi + 4 * j2)) & 15u);
                    z += ee[j2];
                }
                W[G][0] = pk2(ee[0], ee[1]);
                W[G][1] = pk2(ee[2], ee[3]);
            }
        }
        uint Wx[4][2];
#pragma unroll
        for (int G = 0; G < 4; ++G) {
            Wx[G][0] = __shfl_xor(W[G][0], 32);
            Wx[G][1] = __shfl_xor(W[G][1], 32);
        }

        // PV: B-frag for k-slice ks; A = V^T frags
        __builtin_amdgcn_s_setprio(1);
#pragma unroll
        for (int ks = 0; ks < 2; ++ks) {
            union { uint u4[4]; h8 v; } S;
            S.u4[0] = hi ? Wx[2 * ks + 1][0] : W[2 * ks][0];
            S.u4[1] = hi ? Wx[2 * ks + 1][1] : W[2 * ks][1];
            S.u4[2] = hi ? W[2 * ks + 1][0] : Wx[2 * ks][0];
            S.u4[3] = hi ? W[2 * ks + 1][1] : Wx[2 * ks][1];
#pragma unroll
            for (int dg = 0; dg < 2; ++dg) {
                h8 vf = *(const h8*)(LV[half][cur] + (dg * 32 + lm) * 128 +
                                     (((sr * 4 + ks * 2 + hi) ^ (lm & 7)) * 16));
                of[dg] = __builtin_amdgcn_mfma_f32_32x32x16_f16(vf, S.v, of[dg], 0, 0, 0);
            }
        }
        __builtin_amdgcn_s_setprio(0);

        // write next tile into the other buffer (swizzled), then barrier
        if (it < 15) {
            int nb = cur ^ 1;
#pragma unroll
            for (int jj = 0; jj < 2; ++jj) {
                int row = r0 + jj * 32;
                *(uint4*)(LK[half][nb] + row * 128 + (b0 ^ (row & 7)) * 16) = kr[jj];
                *(uint4*)(LV[half][nb] + row * 128 + (b0 ^ (row & 7)) * 16) = vr[jj];
            }
            ac = an;
        }
        __syncthreads();
    }

    // z: lanes l and l^32 share dst col -> sum
    z += __shfl_xor(z, 32);

    // 4-phase combine into CL[64 dst][68] f32 (overlays LK), CLz in LV
    float* CL = (float*)&LK[0][0][0];
    float* CLz = (float*)&LV[0][0][0];
    int gid = half * 2 + sr;
    for (int p = 0; p < 4; ++p) {
        if (gid == p) {
#pragma unroll
            for (int dg = 0; dg < 2; ++dg)
#pragma unroll
                for (int reg = 0; reg < 16; ++reg) {
                    int dim = dg * 32 + (reg & 3) + 8 * (reg >> 2) + 4 * hi;
                    int idx2 = (dc * 32 + lm) * 68 + dim;
                    if (p == 0) CL[idx2] = of[dg][reg];
                    else CL[idx2] += of[dg][reg];
                }
            if (hi == 0) {
                if (p == 0) CLz[dc * 32 + lm] = z;
                else CLz[dc * 32 + lm] += z;
            }
        }
        __syncthreads();
    }

    // coalesced store: thread t -> dst row t>>3, dims (t&7)*8 .. +7
    {
        int dst = t >> 3, d8 = t & 7;
        float inv = 1.0f / CLz[dst];
        float4 o0 = *(float4*)(CL + dst * 68 + d8 * 8);
        float4 o1 = *(float4*)(CL + dst * 68 + d8 * 8 + 4);
        o0.x *= inv; o0.y *= inv; o0.z *= inv; o0.w *= inv;
        o1.x *= inv; o1.y *= inv; o1.z *= inv; o1.w *= inv;
        float* op = out + (size_t)(dst0 + dst) * 512 + h * 64 + d8 * 8;
        *(float4*)op = o0;
        *(float4*)(op + 4) = o1;
    }
}

// ---------------- launch ----------------

extern "C" void kernel_launch(void* const* d_in, const int* in_sizes, int n_in,
                              void* d_out, int out_size, void* d_ws, size_t ws_size,
                              hipStream_t stream) {
    const float* q = (const float*)d_in[0];
    const float* k = (const float*)d_in[1];
    const float* v = (const float*)d_in[2];
    const int* esrc = (const int*)d_in[3];
    const int* edst = (const int*)d_in[4];
    float* out = (float*)d_out;
    const int E = in_sizes[3];

    uchar* A8 = (uchar*)d_ws;                                  // 2MB  A[dst][src] 4-bit
    ushort* kc = (ushort*)(A8 + (size_t)NNODES * NNODES / 2);  // 2MB  fp16 [h][node][dim]
    ushort* vt = kc + (size_t)NHEAD * NNODES * DKDIM;          // 2MB  fp16 [h][dim][node]

    prep1<<<512, 256, 0, stream>>>(k, (uint4*)kc, (uint4*)A8);
    prep2<<<2304, 256, 0, stream>>>(v, vt, esrc, edst, (uint*)A8, E);
    // attn launched 3x (pure function, idempotent): dur differencing vs R15
    // gives attn's true duration: A = (dur_us - 63.6) / 2.
    attn_kernel<<<256, 512, 0, stream>>>(q, kc, vt, A8, out);
    attn_kernel<<<256, 512, 0, stream>>>(q, kc, vt, A8, out);
    attn_kernel<<<256, 512, 0, stream>>>(q, kc, vt, A8, out);
}

// Round 17
// 55.489 us; speedup vs baseline: 2.1442x; 2.1442x over previous
//
#include <hip/hip_runtime.h>

#define NNODES 2048
#define NHEAD 8
#define DKDIM 64

typedef unsigned int uint;
typedef unsigned short ushort;
typedef unsigned char uchar;
typedef __fp16 h2 __attribute__((ext_vector_type(2)));
typedef __fp16 h8 __attribute__((ext_vector_type(8)));
typedef float f16v __attribute__((ext_vector_type(16)));

#define KSCALE 0.18033688011112042f   // 0.125 * log2(e)
#define CLAMP2 14.426950408889634f    // 10 * log2(e)

__device__ __forceinline__ uint pk2(float a, float b) {
    union { h2 h; uint u; } x; x.h = __builtin_amdgcn_cvt_pkrtz(a, b); return x.u;
}

// ---- prep12: one kernel, three parts ----
// blocks 0..511    : k -> fp16 fragment-major kc[frag fK][lane], pre-scaled.
//                    fK = (h*32+ts)*8 + sr*4 + jq ; lane l -> 16B =
//                    K[ts*64+sr*32+(l&31)][(2jq+(l>>5))*8 ..+8]
// blocks 512..767  : v -> fp16 fragment-major vt[frag fV][lane] (transposed).
//                    fV = (h*32+ts)*8 + sr*4 + ks*2 + dg ; lane l -> 16B =
//                    V^T[dg*32+(l&31)][ts*64+(sr*4+ks*2+(l>>5))*8 ..+8]
// blocks 768..1023 : zero A (2MB)
__global__ void prep12(const float* __restrict__ k, const float* __restrict__ v,
                       uint4* __restrict__ kc4, uint4* __restrict__ vt4,
                       uint4* __restrict__ A4) {
    __shared__ float tile[64][65];
    int b = blockIdx.x, t = threadIdx.x;
    if (b < 512) {
        int i = b * 256 + t;
        int f = i >> 6, l = i & 63;
        int jq = f & 3, sr = (f >> 2) & 1, ts = (f >> 3) & 31, h = f >> 8;
        int node = ts * 64 + sr * 32 + (l & 31);
        int dim0 = (2 * jq + (l >> 5)) * 8;
        const float* src = k + (size_t)node * 512 + h * 64 + dim0;
        float4 f0 = *(const float4*)src;
        float4 f1 = *(const float4*)(src + 4);
        uint4 o;
        o.x = pk2(f0.x * KSCALE, f0.y * KSCALE);
        o.y = pk2(f0.z * KSCALE, f0.w * KSCALE);
        o.z = pk2(f1.x * KSCALE, f1.y * KSCALE);
        o.w = pk2(f1.z * KSCALE, f1.w * KSCALE);
        kc4[(size_t)f * 64 + l] = o;
    } else if (b < 768) {
        int bv = b - 512;
        int h = bv & 7, tn = bv >> 3;
        int nl = t >> 2, dq = (t & 3) * 16;
        const float* src = v + (size_t)(tn * 64 + nl) * 512 + h * 64 + dq;
#pragma unroll
        for (int i = 0; i < 4; ++i) {
            float4 f = *(const float4*)(src + i * 4);
            tile[nl][dq + i * 4 + 0] = f.x;
            tile[nl][dq + i * 4 + 1] = f.y;
            tile[nl][dq + i * 4 + 2] = f.z;
            tile[nl][dq + i * 4 + 3] = f.w;
        }
        __syncthreads();
#pragma unroll
        for (int rep = 0; rep < 2; ++rep) {
            int slot = rep * 256 + t;
            int fsub = slot >> 6, l = slot & 63;
            int srv = fsub >> 2, ks = (fsub >> 1) & 1, dg = fsub & 1;
            int dim = dg * 32 + (l & 31);
            int s8 = (srv * 4 + ks * 2 + (l >> 5)) * 8;
            uint4 o;
            o.x = pk2(tile[s8 + 0][dim], tile[s8 + 1][dim]);
            o.y = pk2(tile[s8 + 2][dim], tile[s8 + 3][dim]);
            o.z = pk2(tile[s8 + 4][dim], tile[s8 + 5][dim]);
            o.w = pk2(tile[s8 + 6][dim], tile[s8 + 7][dim]);
            int fV = (h * 32 + tn) * 8 + srv * 4 + ks * 2 + dg;
            vt4[(size_t)fV * 64 + l] = o;
        }
    } else {
        uint4 zz = {0u, 0u, 0u, 0u};
        A4[(size_t)(b - 768) * 512 + t] = zz;
        A4[(size_t)(b - 768) * 512 + t + 256] = zz;
    }
}

// ---- histA: A[dst][src] 4-bit nibbles, packed atomics ----
__global__ void histA(const int* __restrict__ es, const int* __restrict__ ed,
                      uint* __restrict__ A32, int E) {
    int i = blockIdx.x * 256 + threadIdx.x;
    if (i < E) {
        uint idx = (uint)ed[i] * 2048u + (uint)es[i];
        atomicAdd(&A32[idx >> 3], 1u << ((idx & 7) * 4));
    }
}

// ---- dense masked attention: barrier-free main loop, frag-major K/V ----
// Block = 64 dst x 1 head, 512 threads = 8 waves (half, sr, dc). NO LDS and
// NO barriers in the main loop: fragments loaded global->VGPR coalesced from
// the frag-major kc/vt (L2-resident). Per iter per wave: 4 K-frag + 4 V-frag
// + 1 A uint4 loads, 8 MFMA, exp/mask, shfl redistribution (verified R15).
// Software pipeline: V issued at iter top (consumed after exp), K/A one ahead.
// Epilogue combine uses small LDS (18KB) with the only barriers.
__global__ void __launch_bounds__(512, 2) attn_kernel(
    const float* __restrict__ q, const char* __restrict__ kc, const char* __restrict__ vt,
    const uchar* __restrict__ A8, float* __restrict__ out) {
    __shared__ float CL[64 * 68];
    __shared__ float CLz[64];

    int b = blockIdx.x;
    int j = b & 7, idx = b >> 3;
    int dt = (j & 3) * 8 + (idx >> 2);
    int h = (j >> 2) * 4 + (idx & 3);
    int dst0 = dt * 64;
    int t = threadIdx.x;
    int w = t >> 6, half = w >> 2;
    int u = w & 3, sr = u >> 1, dc = u & 1;
    int l = t & 63, lm = l & 31, hi = l >> 5;

    // frag base addresses: frag(ts, x) = ((h*32+ts)*8 + sr*4 + x)*1024 + l*16
    int ts0 = half * 16;
    const char* kBase = kc + ((size_t)(h * 32 + ts0) * 8 + sr * 4) * 1024 + l * 16;
    const char* vBase = vt + ((size_t)(h * 32 + ts0) * 8 + sr * 4) * 1024 + l * 16;
    const char* aRow = (const char*)A8 + (size_t)(dst0 + dc * 32 + lm) * 1024 + sr * 16
                       + ts0 * 32;

    // Q frags (verified): qf[jq] = Q[dst0+dc*32+lm][jq*16 + hi*8 .. +7]
    h8 qf[4];
    {
        const float* qp = q + (size_t)(dst0 + dc * 32 + lm) * 512 + h * 64 + hi * 8;
#pragma unroll
        for (int jq = 0; jq < 4; ++jq) {
            float4 f0 = *(const float4*)(qp + jq * 16);
            float4 f1 = *(const float4*)(qp + jq * 16 + 4);
            union { uint u4[4]; h8 v; } U;
            U.u4[0] = pk2(f0.x, f0.y); U.u4[1] = pk2(f0.z, f0.w);
            U.u4[2] = pk2(f1.x, f1.y); U.u4[3] = pk2(f1.z, f1.w);
            qf[jq] = U.v;
        }
    }

    f16v of[2];
#pragma unroll
    for (int dg = 0; dg < 2; ++dg)
#pragma unroll
        for (int i = 0; i < 16; ++i) of[dg][i] = 0.f;
    float z = 0.f;

    uint4 kcur[4], knxt[4], vcur[4];
    uint4 ac, an;

    // prologue: K frags + A word for tile ts0
#pragma unroll
    for (int jq = 0; jq < 4; ++jq)
        kcur[jq] = *(const uint4*)(kBase + jq * 1024);
    ac = *(const uint4*)aRow;

    for (int it = 0; it < 16; ++it) {
        size_t toff = (size_t)it * 8192;
        // issue V loads for THIS tile (consumed after QK^T+exp: latency hidden)
#pragma unroll
        for (int ks = 0; ks < 2; ++ks)
#pragma unroll
            for (int dg = 0; dg < 2; ++dg)
                vcur[ks * 2 + dg] = *(const uint4*)(vBase + toff + (ks * 2 + dg) * 1024);
        // prefetch next-tile A
        int itn = (it < 15) ? it + 1 : it;
        an = *(const uint4*)(aRow + itn * 32);

        // QK^T: sacc lane (dst=dc*32+lm, hi) reg -> src = sr*32+(reg&3)+8*(reg>>2)+4hi
        f16v sacc;
#pragma unroll
        for (int i = 0; i < 16; ++i) sacc[i] = 0.f;
        __builtin_amdgcn_s_setprio(1);
#pragma unroll
        for (int jq = 0; jq < 4; ++jq) {
            union { uint4 u; h8 v; } KF; KF.u = kcur[jq];
            sacc = __builtin_amdgcn_mfma_f32_32x32x16_f16(KF.v, qf[jq], sacc, 0, 0, 0);
        }
        __builtin_amdgcn_s_setprio(0);

        // prefetch next-tile K frags (consumed next iter; in flight through PV)
#pragma unroll
        for (int jq = 0; jq < 4; ++jq)
            knxt[jq] = *(const uint4*)(kBase + (size_t)itn * 8192 + jq * 1024);

        // exp + 4-bit multiplicity mask + z; pack W[G][p]  (verified R13-R15)
        uint W[4][2];
        {
            const uint* aw4 = (const uint*)&ac;
#pragma unroll
            for (int G = 0; G < 4; ++G) {
                uint aw = aw4[G];
                float ee[4];
#pragma unroll
                for (int j2 = 0; j2 < 4; ++j2) {
                    float sc = fminf(fmaxf(sacc[4 * G + j2], -CLAMP2), CLAMP2);
                    ee[j2] = exp2f(sc) * (float)((aw >> (16 * hi + 4 * j2)) & 15u);
                    z += ee[j2];
                }
                W[G][0] = pk2(ee[0], ee[1]);
                W[G][1] = pk2(ee[2], ee[3]);
            }
        }
        uint Wx[4][2];
#pragma unroll
        for (int G = 0; G < 4; ++G) {
            Wx[G][0] = __shfl_xor(W[G][0], 32);
            Wx[G][1] = __shfl_xor(W[G][1], 32);
        }

        // PV: B-frag from W/Wx; A-operand = V^T frags loaded this iter
        __builtin_amdgcn_s_setprio(1);
#pragma unroll
        for (int ks = 0; ks < 2; ++ks) {
            union { uint u4[4]; h8 v; } S;
            S.u4[0] = hi ? Wx[2 * ks + 1][0] : W[2 * ks][0];
            S.u4[1] = hi ? Wx[2 * ks + 1][1] : W[2 * ks][1];
            S.u4[2] = hi ? W[2 * ks + 1][0] : Wx[2 * ks][0];
            S.u4[3] = hi ? W[2 * ks + 1][1] : Wx[2 * ks][1];
#pragma unroll
            for (int dg = 0; dg < 2; ++dg) {
                union { uint4 u; h8 v; } VF; VF.u = vcur[ks * 2 + dg];
                of[dg] = __builtin_amdgcn_mfma_f32_32x32x16_f16(VF.v, S.v, of[dg], 0, 0, 0);
            }
        }
        __builtin_amdgcn_s_setprio(0);

#pragma unroll
        for (int jq = 0; jq < 4; ++jq) kcur[jq] = knxt[jq];
        ac = an;
    }

    // z: lanes l and l^32 share dst col -> sum
    z += __shfl_xor(z, 32);

    // 4-phase combine into CL[64 dst][68] f32, CLz (the only barriers)
    int gid = half * 2 + sr;
    for (int p = 0; p < 4; ++p) {
        if (gid == p) {
#pragma unroll
            for (int dg = 0; dg < 2; ++dg)
#pragma unroll
                for (int reg = 0; reg < 16; ++reg) {
                    int dim = dg * 32 + (reg & 3) + 8 * (reg >> 2) + 4 * hi;
                    int idx2 = (dc * 32 + lm) * 68 + dim;
                    if (p == 0) CL[idx2] = of[dg][reg];
                    else CL[idx2] += of[dg][reg];
                }
            if (hi == 0) {
                if (p == 0) CLz[dc * 32 + lm] = z;
                else CLz[dc * 32 + lm] += z;
            }
        }
        __syncthreads();
    }

    // coalesced store: thread t -> dst row t>>3, dims (t&7)*8 .. +7
    {
        int dst = t >> 3, d8 = t & 7;
        float inv = 1.0f / CLz[dst];
        float4 o0 = *(float4*)(CL + dst * 68 + d8 * 8);
        float4 o1 = *(float4*)(CL + dst * 68 + d8 * 8 + 4);
        o0.x *= inv; o0.y *= inv; o0.z *= inv; o0.w *= inv;
        o1.x *= inv; o1.y *= inv; o1.z *= inv; o1.w *= inv;
        float* op = out + (size_t)(dst0 + dst) * 512 + h * 64 + d8 * 8;
        *(float4*)op = o0;
        *(float4*)(op + 4) = o1;
    }
}

// ---------------- launch ----------------

extern "C" void kernel_launch(void* const* d_in, const int* in_sizes, int n_in,
                              void* d_out, int out_size, void* d_ws, size_t ws_size,
                              hipStream_t stream) {
    const float* q = (const float*)d_in[0];
    const float* k = (const float*)d_in[1];
    const float* v = (const float*)d_in[2];
    const int* esrc = (const int*)d_in[3];
    const int* edst = (const int*)d_in[4];
    float* out = (float*)d_out;
    const int E = in_sizes[3];

    uchar* A8 = (uchar*)d_ws;                                  // 2MB  A[dst][src] 4-bit
    char* kc = (char*)(A8 + (size_t)NNODES * NNODES / 2);      // 2MB  fp16 frag-major K
    char* vt = kc + (size_t)NHEAD * NNODES * DKDIM * 2;        // 2MB  fp16 frag-major V^T

    prep12<<<1024, 256, 0, stream>>>(k, v, (uint4*)kc, (uint4*)vt, (uint4*)A8);
    histA<<<(E + 255) / 256, 256, 0, stream>>>(esrc, edst, (uint*)A8, E);
    attn_kernel<<<256, 512, 0, stream>>>(q, kc, vt, A8, out);
}